// Round 1
// baseline (1310.335 us; speedup 1.0000x reference)
//
#include <hip/hip_runtime.h>

#define NN 100000
#define NE 3200000
#define DD 256
#define NCHUNK 98  // ceil(NN/1024)

// ---------- helpers ----------
static __device__ __forceinline__ unsigned short f2bf(float f) {
    // round-to-nearest-even fp32 -> bf16
    unsigned u = __float_as_uint(f);
    return (unsigned short)((u + 0x7fffu + ((u >> 16) & 1u)) >> 16);
}

// ---------- degree ----------
__global__ void k_init_deg(int* __restrict__ deg) {
    int i = blockIdx.x * 256 + threadIdx.x;
    if (i < NN) deg[i] = 1;  // unit self-loop
}

__global__ void k_count(const int* __restrict__ src, int* __restrict__ deg) {
    int stride = gridDim.x * blockDim.x;
    for (int e = blockIdx.x * blockDim.x + threadIdx.x; e < NE; e += stride)
        atomicAdd(&deg[src[e]], 1);
}

// ---------- two-level exclusive scan of cnt = deg-1 ----------
__global__ void k_chunksum(const int* __restrict__ deg, int* __restrict__ csum) {
    __shared__ int s[256];
    int b = blockIdx.x, t = threadIdx.x;
    int base = b * 1024 + t * 4;
    int sum = 0;
#pragma unroll
    for (int j = 0; j < 4; ++j) {
        int i = base + j;
        if (i < NN) sum += deg[i] - 1;
    }
    s[t] = sum;
    __syncthreads();
    for (int d = 128; d > 0; d >>= 1) {
        if (t < d) s[t] += s[t + d];
        __syncthreads();
    }
    if (t == 0) csum[b] = s[0];
}

__global__ void k_scanchunks(int* __restrict__ csum) {
    if (blockIdx.x == 0 && threadIdx.x == 0) {
        int run = 0;
        for (int c = 0; c < NCHUNK; ++c) {
            int v = csum[c];
            csum[c] = run;
            run += v;
        }
    }
}

__global__ void k_scanwithin(const int* __restrict__ deg, const int* __restrict__ csum,
                             int* __restrict__ offs, int* __restrict__ woff,
                             float* __restrict__ dinv) {
    __shared__ int s[256];
    int b = blockIdx.x, t = threadIdx.x;
    int base = b * 1024 + t * 4;
    int c[4];
#pragma unroll
    for (int j = 0; j < 4; ++j) {
        int i = base + j;
        c[j] = (i < NN) ? deg[i] - 1 : 0;
    }
    int tsum = c[0] + c[1] + c[2] + c[3];
    s[t] = tsum;
    __syncthreads();
    for (int d = 1; d < 256; d <<= 1) {
        int v = (t >= d) ? s[t - d] : 0;
        __syncthreads();
        s[t] += v;
        __syncthreads();
    }
    int run = s[t] - tsum + csum[b];  // exclusive prefix + chunk offset
#pragma unroll
    for (int j = 0; j < 4; ++j) {
        int i = base + j;
        if (i < NN) {
            offs[i] = run;
            woff[i] = run;
            dinv[i] = 1.0f / (float)deg[i];
            run += c[j];
        }
    }
}

// ---------- CSR scatter ----------
__global__ void k_scatter(const int* __restrict__ src, const int* __restrict__ dst,
                          int* __restrict__ woff, int* __restrict__ adj) {
    int stride = gridDim.x * blockDim.x;
    for (int e = blockIdx.x * blockDim.x + threadIdx.x; e < NE; e += stride) {
        int s = src[e];
        int pos = atomicAdd(&woff[s], 1);
        adj[pos] = dst[e];
    }
}

// ---------- Y = X @ W  (fp32 vector GEMM, bf16 output) ----------
__global__ __launch_bounds__(256) void k_gemm(const float* __restrict__ X,
                                              const float* __restrict__ W,
                                              unsigned short* __restrict__ Y) {
    __shared__ __align__(16) float As[32 * 260];  // 32 rows x 256 + pad 4
    int tid = threadIdx.x;
    int tx = tid & 63;   // column group: cols 4*tx .. 4*tx+3
    int ty = tid >> 6;   // 0..3 -> rows ty*8 .. ty*8+7
    int row0 = blockIdx.x * 32;

    // stage A tile (coalesced float4, conflict-free LDS writes)
    const float4* X4 = (const float4*)X;
#pragma unroll
    for (int it = 0; it < 8; ++it) {
        int idx = it * 256 + tid;  // float4 index in tile, 0..2047
        int r = idx >> 6;          // 64 float4 per row
        int k4 = idx & 63;
        float4 v = X4[(size_t)(row0 + r) * 64 + k4];
        *(float4*)&As[r * 260 + k4 * 4] = v;
    }
    __syncthreads();

    float4 acc[8];
#pragma unroll
    for (int r = 0; r < 8; ++r) acc[r] = make_float4(0.f, 0.f, 0.f, 0.f);

    const float4* W4 = (const float4*)W;
    for (int kb = 0; kb < 256; kb += 4) {
        float4 w0 = W4[(kb + 0) * 64 + tx];
        float4 w1 = W4[(kb + 1) * 64 + tx];
        float4 w2 = W4[(kb + 2) * 64 + tx];
        float4 w3 = W4[(kb + 3) * 64 + tx];
#pragma unroll
        for (int rr = 0; rr < 8; ++rr) {
            float4 a = *(const float4*)&As[(ty * 8 + rr) * 260 + kb];  // wave-broadcast
            acc[rr].x += a.x * w0.x + a.y * w1.x + a.z * w2.x + a.w * w3.x;
            acc[rr].y += a.x * w0.y + a.y * w1.y + a.z * w2.y + a.w * w3.y;
            acc[rr].z += a.x * w0.z + a.y * w1.z + a.z * w2.z + a.w * w3.z;
            acc[rr].w += a.x * w0.w + a.y * w1.w + a.z * w2.w + a.w * w3.w;
        }
    }

#pragma unroll
    for (int rr = 0; rr < 8; ++rr) {
        int row = row0 + ty * 8 + rr;
        ushort4 o;
        o.x = f2bf(acc[rr].x);
        o.y = f2bf(acc[rr].y);
        o.z = f2bf(acc[rr].z);
        o.w = f2bf(acc[rr].w);
        *(ushort4*)&Y[(size_t)row * 256 + tx * 4] = o;
    }
}

// ---------- out = A_hat @ Y  (bf16 gather, fp32 accumulate) ----------
__global__ __launch_bounds__(256) void k_spmm(const unsigned int* __restrict__ Y2,  // bf16 pairs
                                              const int* __restrict__ adj,
                                              const int* __restrict__ offs,
                                              const int* __restrict__ deg,
                                              const float* __restrict__ dinv,
                                              float* __restrict__ out) {
    int sub = threadIdx.x >> 7;  // two nodes per block
    int p = threadIdx.x & 127;   // bf16-pair index -> cols 2p, 2p+1
    int i = blockIdx.x * 2 + sub;
    if (i >= NN) return;

    float wi = dinv[i];
    unsigned v = Y2[(size_t)i * 128 + p];
    float a0 = __uint_as_float(v << 16) * wi;
    float a1 = __uint_as_float(v & 0xffff0000u) * wi;

    int off = offs[i];
    int cnt = deg[i] - 1;
    for (int k = 0; k < cnt; ++k) {
        int j = adj[off + k];
        float wj = dinv[j];
        unsigned u = Y2[(size_t)j * 128 + p];
        a0 = fmaf(__uint_as_float(u << 16), wj, a0);
        a1 = fmaf(__uint_as_float(u & 0xffff0000u), wj, a1);
    }
    ((float2*)out)[(size_t)i * 128 + p] = make_float2(a0, a1);
}

extern "C" void kernel_launch(void* const* d_in, const int* in_sizes, int n_in,
                              void* d_out, int out_size, void* d_ws, size_t ws_size,
                              hipStream_t stream) {
    const float* X = (const float*)d_in[0];
    const int* ei = (const int*)d_in[1];
    const float* W = (const float*)d_in[2];
    const int* src = ei;       // edge_index[0]
    const int* dst = ei + NE;  // edge_index[1]
    float* out = (float*)d_out;

    // workspace carve (ws is re-poisoned before every call -> rebuild everything)
    char* p = (char*)d_ws;
    auto alloc = [&](size_t bytes) {
        void* r = (void*)p;
        p += (bytes + 511) & ~(size_t)511;
        return r;
    };
    int* deg = (int*)alloc((size_t)NN * 4);
    int* offs = (int*)alloc((size_t)NN * 4);
    int* woff = (int*)alloc((size_t)NN * 4);
    int* csum = (int*)alloc((size_t)NCHUNK * 4);
    int* adj = (int*)alloc((size_t)NE * 4);
    float* dinv = (float*)alloc((size_t)NN * 4);
    unsigned short* Y = (unsigned short*)alloc((size_t)NN * DD * 2);

    k_init_deg<<<(NN + 255) / 256, 256, 0, stream>>>(deg);
    k_count<<<2048, 256, 0, stream>>>(src, deg);
    k_chunksum<<<NCHUNK, 256, 0, stream>>>(deg, csum);
    k_scanchunks<<<1, 64, 0, stream>>>(csum);
    k_scanwithin<<<NCHUNK, 256, 0, stream>>>(deg, csum, offs, woff, dinv);
    k_scatter<<<2048, 256, 0, stream>>>(src, dst, woff, adj);
    k_gemm<<<NN / 32, 256, 0, stream>>>(X, W, Y);
    k_spmm<<<NN / 2, 256, 0, stream>>>((const unsigned int*)Y, adj, offs, deg, dinv, out);
}

// Round 2
// 734.909 us; speedup vs baseline: 1.7830x; 1.7830x over previous
//
#include <hip/hip_runtime.h>

#define NN 100000
#define NE 3200000
#define DD 256
#define NCHUNK 98  // ceil(NN/1024)

// ---------- helpers ----------
static __device__ __forceinline__ unsigned short f2bf(float f) {
    // round-to-nearest-even fp32 -> bf16
    unsigned u = __float_as_uint(f);
    return (unsigned short)((u + 0x7fffu + ((u >> 16) & 1u)) >> 16);
}
static __device__ __forceinline__ float bflo(unsigned v) { return __uint_as_float(v << 16); }
static __device__ __forceinline__ float bfhi(unsigned v) { return __uint_as_float(v & 0xffff0000u); }

// ---------- degree ----------
__global__ void k_init_deg(int* __restrict__ deg) {
    int i = blockIdx.x * 256 + threadIdx.x;
    if (i < NN) deg[i] = 1;  // unit self-loop
}

__global__ void k_count(const int* __restrict__ src, int* __restrict__ deg) {
    int stride = gridDim.x * blockDim.x;
    for (int e = blockIdx.x * blockDim.x + threadIdx.x; e < NE; e += stride)
        atomicAdd(&deg[src[e]], 1);
}

// ---------- two-level exclusive scan of cnt = deg-1 ----------
__global__ void k_chunksum(const int* __restrict__ deg, int* __restrict__ csum) {
    __shared__ int s[256];
    int b = blockIdx.x, t = threadIdx.x;
    int base = b * 1024 + t * 4;
    int sum = 0;
#pragma unroll
    for (int j = 0; j < 4; ++j) {
        int i = base + j;
        if (i < NN) sum += deg[i] - 1;
    }
    s[t] = sum;
    __syncthreads();
    for (int d = 128; d > 0; d >>= 1) {
        if (t < d) s[t] += s[t + d];
        __syncthreads();
    }
    if (t == 0) csum[b] = s[0];
}

__global__ void k_scanchunks(int* __restrict__ csum) {
    if (blockIdx.x == 0 && threadIdx.x == 0) {
        int run = 0;
        for (int c = 0; c < NCHUNK; ++c) {
            int v = csum[c];
            csum[c] = run;
            run += v;
        }
    }
}

__global__ void k_scanwithin(const int* __restrict__ deg, const int* __restrict__ csum,
                             int* __restrict__ offs, int* __restrict__ woff,
                             float* __restrict__ dinv) {
    __shared__ int s[256];
    int b = blockIdx.x, t = threadIdx.x;
    int base = b * 1024 + t * 4;
    int c[4];
#pragma unroll
    for (int j = 0; j < 4; ++j) {
        int i = base + j;
        c[j] = (i < NN) ? deg[i] - 1 : 0;
    }
    int tsum = c[0] + c[1] + c[2] + c[3];
    s[t] = tsum;
    __syncthreads();
    for (int d = 1; d < 256; d <<= 1) {
        int v = (t >= d) ? s[t - d] : 0;
        __syncthreads();
        s[t] += v;
        __syncthreads();
    }
    int run = s[t] - tsum + csum[b];  // exclusive prefix + chunk offset
#pragma unroll
    for (int j = 0; j < 4; ++j) {
        int i = base + j;
        if (i < NN) {
            offs[i] = run;
            woff[i] = run;
            dinv[i] = 1.0f / (float)deg[i];
            run += c[j];
        }
    }
}

// ---------- CSR scatter: pack (dst, 1/deg[dst]) per edge ----------
__global__ void k_scatter(const int* __restrict__ src, const int* __restrict__ dst,
                          const float* __restrict__ dinv,
                          int* __restrict__ woff, int2* __restrict__ ejw) {
    int stride = gridDim.x * blockDim.x;
    for (int e = blockIdx.x * blockDim.x + threadIdx.x; e < NE; e += stride) {
        int s = src[e];
        int d = dst[e];
        float w = dinv[d];
        int pos = atomicAdd(&woff[s], 1);
        ejw[pos] = make_int2(d, __float_as_int(w));
    }
}

// ---------- Wt = bf16(W^T)  (tiny: 256x256) ----------
__global__ void k_wt(const float* __restrict__ W, unsigned short* __restrict__ Wt) {
    int idx = blockIdx.x * 256 + threadIdx.x;  // 65536
    int n = idx >> 8, k = idx & 255;
    Wt[n * 256 + k] = f2bf(W[k * 256 + n]);
}

// ---------- Y = bf16(X @ W)  via MFMA bf16 ----------
// Block: 256 thr = 4 waves. Tile M=32 (3125 blocks exact), N=256 full.
// Wave w computes rows 0..31 x cols 64w..64w+63 (2 mtiles x 4 ntiles of 16x16).
__global__ __launch_bounds__(256) void k_gemm(const float* __restrict__ X,
                                              const unsigned short* __restrict__ Wt,
                                              unsigned short* __restrict__ Y) {
    using bf16x8 = __attribute__((ext_vector_type(8))) short;
    using f32x4 = __attribute__((ext_vector_type(4))) float;
    __shared__ unsigned short As[32 * 40];   // [row][k], pad 32->40 (keeps 16B align)
    __shared__ unsigned short Bs[256 * 40];  // [n][k]

    int tid = threadIdx.x;
    int lane = tid & 63, w = tid >> 6;
    int row0 = blockIdx.x * 32;

    f32x4 acc[2][4];
#pragma unroll
    for (int m = 0; m < 2; ++m)
#pragma unroll
        for (int nt = 0; nt < 4; ++nt) acc[m][nt] = (f32x4){0.f, 0.f, 0.f, 0.f};

    int ar = tid >> 3;        // A staging: row 0..31
    int ak = (tid & 7) * 4;   // k within tile: 0,4,...,28
    int mrow = lane & 15, quad = lane >> 4;

    for (int k0 = 0; k0 < 256; k0 += 32) {
        // stage A (fp32 -> bf16)
        float4 xv = *(const float4*)(X + (size_t)(row0 + ar) * 256 + k0 + ak);
        ushort4 xb;
        xb.x = f2bf(xv.x); xb.y = f2bf(xv.y); xb.z = f2bf(xv.z); xb.w = f2bf(xv.w);
        *(ushort4*)&As[ar * 40 + ak] = xb;
        // stage B (bf16 copy of Wt rows, coalesced 16B)
#pragma unroll
        for (int it = 0; it < 4; ++it) {
            int g = it * 256 + tid;
            int n = g >> 2, kq = g & 3;
            uint4 bv = *(const uint4*)(Wt + (size_t)n * 256 + k0 + kq * 8);
            *(uint4*)&Bs[n * 40 + kq * 8] = bv;
        }
        __syncthreads();

        bf16x8 af[2], bfr[4];
#pragma unroll
        for (int m = 0; m < 2; ++m)
            af[m] = *(const bf16x8*)&As[(m * 16 + mrow) * 40 + quad * 8];
#pragma unroll
        for (int nt = 0; nt < 4; ++nt)
            bfr[nt] = *(const bf16x8*)&Bs[(w * 64 + nt * 16 + mrow) * 40 + quad * 8];
#pragma unroll
        for (int m = 0; m < 2; ++m)
#pragma unroll
            for (int nt = 0; nt < 4; ++nt)
                acc[m][nt] = __builtin_amdgcn_mfma_f32_16x16x32_bf16(af[m], bfr[nt], acc[m][nt], 0, 0, 0);
        __syncthreads();
    }

    // epilogue: C/D layout col=lane&15, row=quad*4+reg
#pragma unroll
    for (int m = 0; m < 2; ++m)
#pragma unroll
        for (int nt = 0; nt < 4; ++nt)
#pragma unroll
            for (int r = 0; r < 4; ++r) {
                int row = row0 + m * 16 + quad * 4 + r;
                int col = w * 64 + nt * 16 + mrow;
                Y[(size_t)row * 256 + col] = f2bf(acc[m][nt][r]);
            }
}

// ---------- out = A_hat @ Y : one wave per node, unroll-4 gathers ----------
__global__ __launch_bounds__(256) void k_spmm(const uint2* __restrict__ Yp,  // row i = Yp + i*64 (8B = 4 bf16)
                                              const int2* __restrict__ ejw,
                                              const int* __restrict__ offs,
                                              const int* __restrict__ deg,
                                              const float* __restrict__ dinv,
                                              float* __restrict__ out) {
    int w = threadIdx.x >> 6;
    int lane = threadIdx.x & 63;
    int i = blockIdx.x * 4 + w;  // grid 25000 exact

    float wi = dinv[i];
    uint2 v = Yp[(size_t)i * 64 + lane];
    float a0 = bflo(v.x) * wi, a1 = bfhi(v.x) * wi;
    float a2 = bflo(v.y) * wi, a3 = bfhi(v.y) * wi;

    int off = offs[i];
    int cnt = deg[i] - 1;
    const int2* e = ejw + off;

    for (int k = 0; k < cnt; k += 4) {
        int2 p[4];
        float wj[4];
#pragma unroll
        for (int u = 0; u < 4; ++u) {
            int idx = k + u;
            int cl = idx < cnt ? idx : cnt - 1;  // clamp: no OOB, weight 0 below
            p[u] = e[cl];
            wj[u] = (idx < cnt) ? __int_as_float(p[u].y) : 0.f;
        }
        uint2 r[4];
#pragma unroll
        for (int u = 0; u < 4; ++u) r[u] = Yp[(size_t)p[u].x * 64 + lane];
#pragma unroll
        for (int u = 0; u < 4; ++u) {
            a0 = fmaf(bflo(r[u].x), wj[u], a0);
            a1 = fmaf(bfhi(r[u].x), wj[u], a1);
            a2 = fmaf(bflo(r[u].y), wj[u], a2);
            a3 = fmaf(bfhi(r[u].y), wj[u], a3);
        }
    }

    *(float4*)(out + (size_t)i * 256 + lane * 4) = make_float4(a0, a1, a2, a3);
}

extern "C" void kernel_launch(void* const* d_in, const int* in_sizes, int n_in,
                              void* d_out, int out_size, void* d_ws, size_t ws_size,
                              hipStream_t stream) {
    const float* X = (const float*)d_in[0];
    const int* ei = (const int*)d_in[1];
    const float* W = (const float*)d_in[2];
    const int* src = ei;       // edge_index[0]
    const int* dst = ei + NE;  // edge_index[1]
    float* out = (float*)d_out;

    // workspace carve (ws re-poisoned before every call -> rebuild everything)
    char* p = (char*)d_ws;
    auto alloc = [&](size_t bytes) {
        void* r = (void*)p;
        p += (bytes + 511) & ~(size_t)511;
        return r;
    };
    int* deg = (int*)alloc((size_t)NN * 4);
    int* offs = (int*)alloc((size_t)NN * 4);
    int* woff = (int*)alloc((size_t)NN * 4);
    int* csum = (int*)alloc((size_t)NCHUNK * 4);
    float* dinv = (float*)alloc((size_t)NN * 4);
    int2* ejw = (int2*)alloc(((size_t)NE + 8) * 8);
    unsigned short* Wt = (unsigned short*)alloc((size_t)DD * DD * 2);
    unsigned short* Y = (unsigned short*)alloc((size_t)NN * DD * 2);

    k_init_deg<<<(NN + 255) / 256, 256, 0, stream>>>(deg);
    k_count<<<2048, 256, 0, stream>>>(src, deg);
    k_chunksum<<<NCHUNK, 256, 0, stream>>>(deg, csum);
    k_scanchunks<<<1, 64, 0, stream>>>(csum);
    k_scanwithin<<<NCHUNK, 256, 0, stream>>>(deg, csum, offs, woff, dinv);
    k_scatter<<<2048, 256, 0, stream>>>(src, dst, dinv, woff, ejw);
    k_wt<<<DD * DD / 256, 256, 0, stream>>>(W, Wt);
    k_gemm<<<NN / 32, 256, 0, stream>>>(X, Wt, Y);
    k_spmm<<<NN / 4, 256, 0, stream>>>((const uint2*)Y, ejw, offs, deg, dinv, out);
}